// Round 7
// baseline (69.371 us; speedup 1.0000x reference)
//
#include <hip/hip_runtime.h>

#define B 128
#define N 512
#define D 256
#define S 8

typedef float f32x4 __attribute__((ext_vector_type(4)));

#define GLOBAL_AS __attribute__((address_space(1)))
#define LDS_AS    __attribute__((address_space(3)))

// async global->LDS DMA, 16B per lane. Per-lane global addr; LDS dest is
// wave-uniform base (HW writes base + lane*16).
__device__ __forceinline__ void stage16(const float* g, float* l) {
    __builtin_amdgcn_global_load_lds((const GLOBAL_AS void*)g,
                                     (LDS_AS void*)l, 16, 0, 0);
}

// ---------------------------------------------------------------------------
// K1 (fused): grid (16, B), block 256.
//   role in [0,8):  edge chunk -> em[b,:] += sum_i edge[b,i,:]*ka[b,i]
//     64x512-float contiguous chunk streamed via 2x16KB LDS dbuf,
//     global_load_lds_dwordx4, counted vmcnt(4), raw s_barrier.
//   role in [8,16): node chunk -> kf[b,:] += sum_n node[b,n,:]*ka[b,n]
//     64x256-float chunk via 2x8KB dbuf, vmcnt(2); + out_att (NT) + out_sp.
// R2-R6 lesson: compiler pins VGPR=32 and sinks all register batches ->
// MLP must come from LDS-destined DMA, not VGPR-resident loads.
// ---------------------------------------------------------------------------
__global__ __launch_bounds__(256) void k1_fused(
    const float* __restrict__ node, const float* __restrict__ edge,
    const float* __restrict__ att, const float* __restrict__ spi,
    float* __restrict__ out_att, float* __restrict__ out_sp,
    float* __restrict__ kf, float* __restrict__ em) {
    const int b = blockIdx.y;
    const int role = blockIdx.x;
    const int tid = threadIdx.x;
    const int lane = tid & 63;
    const int w = tid >> 6;          // wave 0..3

    __shared__ float sm[8192];       // 32KB stage area (dbuf)
    __shared__ float kal[64];
    __shared__ float sps[S];

    if (tid < S) sps[tid] = spi[b * S + tid];
    __syncthreads();

    if (role < 8) {
        // ---- edge: rows i0..i0+63, full 512-col width ----
        const int i0 = role * 64;
        if (tid < 64) {
            const float4* a = reinterpret_cast<const float4*>(att + ((size_t)(b * N + i0 + tid)) * S);
            float4 a0 = a[0], a1 = a[1];
            kal[tid] = a0.x * sps[0] + a0.y * sps[1] + a0.z * sps[2] + a0.w * sps[3]
                     + a1.x * sps[4] + a1.y * sps[5] + a1.z * sps[6] + a1.w * sps[7];
        }
        __syncthreads();                    // drains vmcnt to 0 before staging

        const float* gbase = edge + ((size_t)b * N + i0) * N;   // 64*512 floats
        float* stA = sm;                     // 4096 floats (16KB)
        float* stB = sm + 4096;
        const int r = tid >> 7;              // row parity 0/1
        const int c = tid & 127;             // float4 col of N

        // prologue: stage phase 0 into stA (4 x 1KB per wave)
        {
            const float* g0 = gbase + w * 1024 + lane * 4;
            float* l0 = stA + w * 1024;
            stage16(g0 + 0,   l0 + 0);
            stage16(g0 + 256, l0 + 256);
            stage16(g0 + 512, l0 + 512);
            stage16(g0 + 768, l0 + 768);
        }
        f32x4 acc = {0.f, 0.f, 0.f, 0.f};
        for (int t = 0; t < 8; ++t) {
            const int h = t & 1;
            if (t < 7) {
                const float* g = gbase + (t + 1) * 4096 + w * 1024 + lane * 4;
                float* l = (h ? stA : stB) + w * 1024;
                stage16(g + 0,   l + 0);
                stage16(g + 256, l + 256);
                stage16(g + 512, l + 512);
                stage16(g + 768, l + 768);
                asm volatile("s_waitcnt vmcnt(4)" ::: "memory");
            } else {
                asm volatile("s_waitcnt vmcnt(0)" ::: "memory");
            }
            __builtin_amdgcn_sched_barrier(0);
            __builtin_amdgcn_s_barrier();
            const f32x4* lb4 = reinterpret_cast<const f32x4*>(h ? stB : stA);
            #pragma unroll
            for (int k = 0; k < 4; ++k) {
                float kv = kal[t * 8 + 2 * k + r];
                acc += kv * lb4[(2 * k + r) * 128 + c];
            }
            __builtin_amdgcn_sched_barrier(0);
            __builtin_amdgcn_s_barrier();
        }
        float* dst = em + b * N + c * 4;
        unsafeAtomicAdd(dst + 0, acc.x);
        unsafeAtomicAdd(dst + 1, acc.y);
        unsafeAtomicAdd(dst + 2, acc.z);
        unsafeAtomicAdd(dst + 3, acc.w);
    } else {
        // ---- node: rows n0..n0+63, 256-col width (+ stack outputs) ----
        const int n0 = (role - 8) * 64;
        if (tid < 64) {
            const float4* a = reinterpret_cast<const float4*>(att + ((size_t)(b * N + n0 + tid)) * S);
            float4 a0 = a[0], a1 = a[1];
            kal[tid] = a0.x * sps[0] + a0.y * sps[1] + a0.z * sps[2] + a0.w * sps[3]
                     + a1.x * sps[4] + a1.y * sps[5] + a1.z * sps[6] + a1.w * sps[7];
            f32x4 o0 = {a0.x * (1.f - sps[0]), a0.y * (1.f - sps[1]),
                        a0.z * (1.f - sps[2]), a0.w * (1.f - sps[3])};
            f32x4 o1 = {a1.x * (1.f - sps[4]), a1.y * (1.f - sps[5]),
                        a1.z * (1.f - sps[6]), a1.w * (1.f - sps[7])};
            f32x4* oa = reinterpret_cast<f32x4*>(out_att + ((size_t)(b * N + n0 + tid)) * S);
            __builtin_nontemporal_store(o0, &oa[0]);
            __builtin_nontemporal_store(o1, &oa[1]);
        }
        if (role == 8 && tid < S) {
            float v = (tid < S - 1) ? sps[tid + 1] : 0.0f;
            if (tid == 0) v += sps[0];
            out_sp[b * S + tid] = v;
        }
        __syncthreads();                    // drains vmcnt (att loads + stores)

        const float* gbase = node + ((size_t)b * N + n0) * D;   // 64*256 floats
        float* stA = sm;                     // 2048 floats (8KB)
        float* stB = sm + 2048;
        const int c = tid & 63;              // float4 col of D
        // r == w (tid>>6): rows {w, 4+w} of each 8-row phase

        {
            const float* g0 = gbase + w * 512 + lane * 4;
            float* l0 = stA + w * 512;
            stage16(g0 + 0,   l0 + 0);
            stage16(g0 + 256, l0 + 256);
        }
        f32x4 acc = {0.f, 0.f, 0.f, 0.f};
        for (int t = 0; t < 8; ++t) {
            const int h = t & 1;
            if (t < 7) {
                const float* g = gbase + (t + 1) * 2048 + w * 512 + lane * 4;
                float* l = (h ? stA : stB) + w * 512;
                stage16(g + 0,   l + 0);
                stage16(g + 256, l + 256);
                asm volatile("s_waitcnt vmcnt(2)" ::: "memory");
            } else {
                asm volatile("s_waitcnt vmcnt(0)" ::: "memory");
            }
            __builtin_amdgcn_sched_barrier(0);
            __builtin_amdgcn_s_barrier();
            const f32x4* lb4 = reinterpret_cast<const f32x4*>(h ? stB : stA);
            #pragma unroll
            for (int k = 0; k < 2; ++k) {
                float kv = kal[t * 8 + 4 * k + w];
                acc += kv * lb4[(4 * k + w) * 64 + c];
            }
            __builtin_amdgcn_sched_barrier(0);
            __builtin_amdgcn_s_barrier();
        }
        // cross-wave reduce: alias red area into upper stage half (staging done)
        f32x4* red = reinterpret_cast<f32x4*>(sm + 4096);
        red[tid] = acc;
        __syncthreads();
        if (tid < 64) {
            f32x4 s = red[c] + red[c + 64] + red[c + 128] + red[c + 192];
            float* dst = kf + b * D + c * 4;
            unsafeAtomicAdd(dst + 0, s.x);
            unsafeAtomicAdd(dst + 1, s.y);
            unsafeAtomicAdd(dst + 2, s.z);
            unsafeAtomicAdd(dst + 3, s.w);
        }
    }
}

// ---------------------------------------------------------------------------
// K2: q[b,d] = bias[d] + sum_k W[d,k] * kf[b,k]   (grid B, block D)
// ---------------------------------------------------------------------------
__global__ void kC_q(const float* __restrict__ Wm,
                     const float* __restrict__ bias,
                     const float* __restrict__ kf,
                     float* __restrict__ q) {
    const int b = blockIdx.x;
    const int d = threadIdx.x;
    __shared__ float kfl[D];
    kfl[d] = kf[b * D + d];
    __syncthreads();
    float acc = bias[d];
    const float4* wrow = reinterpret_cast<const float4*>(Wm + (size_t)d * D);
    const float4* kf4 = reinterpret_cast<const float4*>(kfl);
    float4 w[8];
    for (int k0 = 0; k0 < D / 4; k0 += 8) {
        #pragma unroll
        for (int u = 0; u < 8; ++u) w[u] = wrow[k0 + u];
        #pragma unroll
        for (int u = 0; u < 8; ++u) {
            float4 f = kf4[k0 + u];
            acc += w[u].x * f.x + w[u].y * f.y + w[u].z * f.z + w[u].w * f.w;
        }
    }
    q[b * D + d] = acc;
}

// ---------------------------------------------------------------------------
// K3: out_vm[b,n] = vm[b,n] + em[b,n] * dot(node[b,n,:], q[b,:])
// One wave per row, 32 rows per block. Each wave DMA-stages its own 8 rows
// (8KB) into wave-private LDS (no barriers), vmcnt(0), then dot+shfl-reduce.
// ---------------------------------------------------------------------------
__global__ __launch_bounds__(256) void kD_logits(
    const float* __restrict__ node,
    const float* __restrict__ em,
    const float* __restrict__ q,
    const float* __restrict__ vm,
    float* __restrict__ out_vm) {
    const int row0 = blockIdx.x * 32;
    const int b = row0 / N;
    const int tid = threadIdx.x;
    const int wave = tid >> 6;
    const int lane = tid & 63;
    __shared__ float ql[D];
    __shared__ float sm[8192];           // 4 waves x 2048 floats (8KB each)
    if (tid < D) ql[tid] = q[b * D + tid];
    __syncthreads();                      // also drains the ql loads
    const float4 q4 = reinterpret_cast<const float4*>(ql)[lane];
    const int wr0 = row0 + wave * 8;

    float* myl = sm + wave * 2048;
    const float* g0 = node + (size_t)wr0 * D + lane * 4;
    #pragma unroll
    for (int r = 0; r < 8; ++r)
        stage16(g0 + (size_t)r * D, myl + r * 256);

    float emv = 0.f, vmv = 0.f;
    if (lane < 8) {
        emv = em[wr0 + lane];
        vmv = vm[wr0 + lane];
    }
    asm volatile("s_waitcnt vmcnt(0)" ::: "memory");
    __builtin_amdgcn_sched_barrier(0);

    float myS = 0.f;
    #pragma unroll
    for (int r = 0; r < 8; ++r) {
        const f32x4 v = reinterpret_cast<const f32x4*>(myl + r * 256)[lane];
        float s = v.x * q4.x + v.y * q4.y + v.z * q4.z + v.w * q4.w;
        #pragma unroll
        for (int off = 32; off; off >>= 1) s += __shfl_xor(s, off);
        if (lane == r) myS = s;
    }
    if (lane < 8) {
        out_vm[wr0 + lane] = vmv + emv * myS;
    }
}

extern "C" void kernel_launch(void* const* d_in, const int* in_sizes, int n_in,
                              void* d_out, int out_size, void* d_ws, size_t ws_size,
                              hipStream_t stream) {
    const float* node = (const float*)d_in[0];
    // d_in[1] = query : unused by the reference computation
    const float* edge = (const float*)d_in[2];
    const float* att  = (const float*)d_in[3];
    const float* sp   = (const float*)d_in[4];
    const float* vm   = (const float*)d_in[5];
    const float* Wm   = (const float*)d_in[6];
    const float* bias = (const float*)d_in[7];

    float* out_att = (float*)d_out;                    // B*N*S
    float* out_sp  = out_att + (size_t)B * N * S;      // B*S
    float* out_vm  = out_sp + (size_t)B * S;           // B*N

    float* ws = (float*)d_ws;
    float* kf = ws;                          // B*D (atomic-accumulated -> zero)
    float* em = kf + (size_t)B * D;          // B*N (atomic-accumulated -> zero)
    float* q  = em + (size_t)B * N;          // B*D

    (void)hipMemsetAsync(kf, 0, (size_t)(B * D + B * N) * sizeof(float), stream);

    k1_fused<<<dim3(16, B), 256, 0, stream>>>(node, edge, att, sp,
                                              out_att, out_sp, kf, em);
    kC_q<<<B, D, 0, stream>>>(Wm, bias, kf, q);
    kD_logits<<<(B * N) / 32, 256, 0, stream>>>(node, em, q, vm, out_vm);
}

// Round 8
// 67.120 us; speedup vs baseline: 1.0336x; 1.0336x over previous
//
#include <hip/hip_runtime.h>

#define B 128
#define N 512
#define D 256
#define S 8

typedef float f32x4 __attribute__((ext_vector_type(4)));

// ---------------------------------------------------------------------------
// K1 (fused): grid (8, B), block 256. No atomics, no pre-zeroed buffers.
//   role in [0,4):  edge rows [role*128, +128) -> em_part[role][b][:]
//   role in [4,8):  node rows [(role-4)*128, +128) -> kf_part[role-4][b][:]
//                   + out_att chunk (+ out_sp once)
// R2-R7 lesson: per-dispatch rocprof dur is ~75us fixed overhead (even a
// 15KB fill shows 74us) -- judge by bench dur only. Simple float4 loads
// (R3) beat every ILP/NT/DMA variant; remaining slack is structural
// (graph nodes, memset, atomic drains), so partial-sum buffers replace
// atomics and the memset node disappears.
// ---------------------------------------------------------------------------
__global__ __launch_bounds__(256) void k1_fused(
    const float* __restrict__ node, const float* __restrict__ edge,
    const float* __restrict__ att, const float* __restrict__ spi,
    float* __restrict__ out_att, float* __restrict__ out_sp,
    float* __restrict__ kf_part, float* __restrict__ em_part) {
    const int b = blockIdx.y;
    const int role = blockIdx.x;
    const int tid = threadIdx.x;
    __shared__ float sps[S];
    __shared__ float kal[128];
    __shared__ f32x4 red[256];
    if (tid < S) sps[tid] = spi[b * S + tid];
    __syncthreads();

    if (role < 4) {
        // ---- edge chunk: 128 rows x 512 cols -> em_part[role] ----
        const int i0 = role * 128;
        if (tid < 128) {
            const float4* a = reinterpret_cast<const float4*>(att + ((size_t)(b * N + i0 + tid)) * S);
            float4 a0 = a[0], a1 = a[1];
            kal[tid] = a0.x * sps[0] + a0.y * sps[1] + a0.z * sps[2] + a0.w * sps[3]
                     + a1.x * sps[4] + a1.y * sps[5] + a1.z * sps[6] + a1.w * sps[7];
        }
        __syncthreads();
        const int r = tid >> 7;          // row parity 0/1 (rows 2k + r)
        const int c = tid & 127;         // f32x4 column of N
        const f32x4* base = reinterpret_cast<const f32x4*>(edge + ((size_t)(b * N + i0)) * N)
                          + (size_t)r * (N / 4) + c;
        const size_t rs = 2 * (N / 4);
        f32x4 acc = {0.f, 0.f, 0.f, 0.f};
        f32x4 v[8];
        for (int k0 = 0; k0 < 64; k0 += 8) {
            #pragma unroll
            for (int u = 0; u < 8; ++u) v[u] = base[(size_t)(k0 + u) * rs];
            #pragma unroll
            for (int u = 0; u < 8; ++u) acc += kal[2 * (k0 + u) + r] * v[u];
        }
        red[tid] = acc;
        __syncthreads();
        if (tid < 128) {
            f32x4 s = red[tid] + red[tid + 128];
            reinterpret_cast<f32x4*>(em_part + ((size_t)role * B + b) * N)[tid] = s;
        }
    } else {
        // ---- node chunk: 128 rows x 256 cols -> kf_part[role-4] ----
        const int p = role - 4;
        const int n0 = p * 128;
        if (tid < 128) {
            const float4* a = reinterpret_cast<const float4*>(att + ((size_t)(b * N + n0 + tid)) * S);
            float4 a0 = a[0], a1 = a[1];
            kal[tid] = a0.x * sps[0] + a0.y * sps[1] + a0.z * sps[2] + a0.w * sps[3]
                     + a1.x * sps[4] + a1.y * sps[5] + a1.z * sps[6] + a1.w * sps[7];
            float4 o0 = make_float4(a0.x * (1.f - sps[0]), a0.y * (1.f - sps[1]),
                                    a0.z * (1.f - sps[2]), a0.w * (1.f - sps[3]));
            float4 o1 = make_float4(a1.x * (1.f - sps[4]), a1.y * (1.f - sps[5]),
                                    a1.z * (1.f - sps[6]), a1.w * (1.f - sps[7]));
            float4* oa = reinterpret_cast<float4*>(out_att + ((size_t)(b * N + n0 + tid)) * S);
            oa[0] = o0;
            oa[1] = o1;
        }
        if (p == 0 && tid < S) {
            float v = (tid < S - 1) ? sps[tid + 1] : 0.0f;
            if (tid == 0) v += sps[0];
            out_sp[b * S + tid] = v;
        }
        __syncthreads();
        const int r = tid >> 6;          // row mod 4 (rows 4k + r)
        const int c = tid & 63;          // f32x4 column of D
        const f32x4* base = reinterpret_cast<const f32x4*>(node + ((size_t)(b * N + n0)) * D)
                          + (size_t)r * (D / 4) + c;
        const size_t rs = 4 * (D / 4);
        f32x4 acc = {0.f, 0.f, 0.f, 0.f};
        f32x4 v[8];
        for (int k0 = 0; k0 < 32; k0 += 8) {
            #pragma unroll
            for (int u = 0; u < 8; ++u) v[u] = base[(size_t)(k0 + u) * rs];
            #pragma unroll
            for (int u = 0; u < 8; ++u) acc += kal[4 * (k0 + u) + r] * v[u];
        }
        red[tid] = acc;
        __syncthreads();
        if (tid < 64) {
            f32x4 s = red[c] + red[c + 64] + red[c + 128] + red[c + 192];
            reinterpret_cast<f32x4*>(kf_part + ((size_t)p * B + b) * D)[c] = s;
        }
    }
}

// ---------------------------------------------------------------------------
// K2: q[b,d] = bias[d] + sum_k W[d,k] * (sum_p kf_part[p][b][k])
// grid B, block D; summed kf staged in LDS.
// ---------------------------------------------------------------------------
__global__ void kC_q(const float* __restrict__ Wm,
                     const float* __restrict__ bias,
                     const float* __restrict__ kf_part,
                     float* __restrict__ q) {
    const int b = blockIdx.x;
    const int d = threadIdx.x;
    __shared__ float kfl[D];
    float kv = kf_part[(size_t)b * D + d]
             + kf_part[((size_t)B + b) * D + d]
             + kf_part[((size_t)2 * B + b) * D + d]
             + kf_part[((size_t)3 * B + b) * D + d];
    kfl[d] = kv;
    __syncthreads();
    float acc = bias[d];
    const float4* wrow = reinterpret_cast<const float4*>(Wm + (size_t)d * D);
    const float4* kf4 = reinterpret_cast<const float4*>(kfl);
    float4 w[8];
    for (int k0 = 0; k0 < D / 4; k0 += 8) {
        #pragma unroll
        for (int u = 0; u < 8; ++u) w[u] = wrow[k0 + u];
        #pragma unroll
        for (int u = 0; u < 8; ++u) {
            float4 f = kf4[k0 + u];
            acc += w[u].x * f.x + w[u].y * f.y + w[u].z * f.z + w[u].w * f.w;
        }
    }
    q[b * D + d] = acc;
}

// ---------------------------------------------------------------------------
// K3: out_vm[b,n] = vm[b,n] + (sum_p em_part[p][b][n]) * dot(node[b,n,:], q[b,:])
// one wave per row (64 lanes x float4 = 256 floats); 32 rows per block.
// ---------------------------------------------------------------------------
__global__ void kD_logits(const float* __restrict__ node,
                          const float* __restrict__ em_part,
                          const float* __restrict__ q,
                          const float* __restrict__ vm,
                          float* __restrict__ out_vm) {
    const int row0 = blockIdx.x * 32;
    const int b = row0 / N;
    const int tid = threadIdx.x;
    const int wave = tid >> 6;
    const int lane = tid & 63;
    __shared__ float ql[D];
    if (tid < D) ql[tid] = q[b * D + tid];
    __syncthreads();
    const float4 q4 = reinterpret_cast<const float4*>(ql)[lane];
    const int wr0 = row0 + wave * 8;
    float emv = 0.f, vmv = 0.f;
    if (lane < 8) {
        const int n = wr0 + lane;
        const int nloc = n - b * N;
        emv = em_part[(size_t)b * N + nloc]
            + em_part[((size_t)B + b) * N + nloc]
            + em_part[((size_t)2 * B + b) * N + nloc]
            + em_part[((size_t)3 * B + b) * N + nloc];
        vmv = vm[n];
    }
    float4 v[8];
    #pragma unroll
    for (int r = 0; r < 8; ++r)
        v[r] = reinterpret_cast<const float4*>(node + (size_t)(wr0 + r) * D)[lane];
    float myS = 0.f;
    #pragma unroll
    for (int r = 0; r < 8; ++r) {
        float s = v[r].x * q4.x + v[r].y * q4.y + v[r].z * q4.z + v[r].w * q4.w;
        #pragma unroll
        for (int off = 32; off; off >>= 1) s += __shfl_xor(s, off);
        if (lane == r) myS = s;
    }
    if (lane < 8) {
        out_vm[wr0 + lane] = vmv + emv * myS;
    }
}

extern "C" void kernel_launch(void* const* d_in, const int* in_sizes, int n_in,
                              void* d_out, int out_size, void* d_ws, size_t ws_size,
                              hipStream_t stream) {
    const float* node = (const float*)d_in[0];
    // d_in[1] = query : unused by the reference computation
    const float* edge = (const float*)d_in[2];
    const float* att  = (const float*)d_in[3];
    const float* sp   = (const float*)d_in[4];
    const float* vm   = (const float*)d_in[5];
    const float* Wm   = (const float*)d_in[6];
    const float* bias = (const float*)d_in[7];

    float* out_att = (float*)d_out;                    // B*N*S
    float* out_sp  = out_att + (size_t)B * N * S;      // B*S
    float* out_vm  = out_sp + (size_t)B * S;           // B*N

    float* ws = (float*)d_ws;
    float* em_part = ws;                                   // 4*B*N  (1 MiB)
    float* kf_part = em_part + (size_t)4 * B * N;          // 4*B*D  (0.5 MiB)
    float* q       = kf_part + (size_t)4 * B * D;          // B*D

    k1_fused<<<dim3(8, B), 256, 0, stream>>>(node, edge, att, sp,
                                             out_att, out_sp, kf_part, em_part);
    kC_q<<<B, D, 0, stream>>>(Wm, bias, kf_part, q);
    kD_logits<<<(B * N) / 32, 256, 0, stream>>>(node, em_part, q, vm, out_vm);
}

// Round 10
// 64.042 us; speedup vs baseline: 1.0832x; 1.0481x over previous
//
#include <hip/hip_runtime.h>

#define B 128
#define N 512
#define D 256
#define S 8

typedef float f32x4 __attribute__((ext_vector_type(4)));

// ---- forced-MLP primitives: asm loads cannot be sunk by the scheduler ----
// Each LD8 issues 8 independent global_load_dwordx4 (asm volatile = ordered,
// never elided/sunk). WAIT8 makes the 8 values data-dependent on the
// s_waitcnt (rule #18: "memory" clobber alone doesn't order reg-only
// consumers) and fences with sched_barrier(0).

#define LD1(dst, addr) \
    asm volatile("global_load_dwordx4 %0, %1, off" : "=v"(dst) : "v"(addr))

#define LD8(p, gb, t, stride) \
    LD1(p##0, (gb) + (size_t)((t) * 8 + 0) * (stride)); \
    LD1(p##1, (gb) + (size_t)((t) * 8 + 1) * (stride)); \
    LD1(p##2, (gb) + (size_t)((t) * 8 + 2) * (stride)); \
    LD1(p##3, (gb) + (size_t)((t) * 8 + 3) * (stride)); \
    LD1(p##4, (gb) + (size_t)((t) * 8 + 4) * (stride)); \
    LD1(p##5, (gb) + (size_t)((t) * 8 + 5) * (stride)); \
    LD1(p##6, (gb) + (size_t)((t) * 8 + 6) * (stride)); \
    LD1(p##7, (gb) + (size_t)((t) * 8 + 7) * (stride))

#define WAIT8(p, cnt) \
    asm volatile("s_waitcnt vmcnt(" cnt ")" \
        : "+v"(p##0), "+v"(p##1), "+v"(p##2), "+v"(p##3), \
          "+v"(p##4), "+v"(p##5), "+v"(p##6), "+v"(p##7) :: "memory"); \
    __builtin_amdgcn_sched_barrier(0)

#define CONS8(p, kbase, t) \
    acc += (kbase)[(t) * 8 + 0] * p##0; \
    acc += (kbase)[(t) * 8 + 1] * p##1; \
    acc += (kbase)[(t) * 8 + 2] * p##2; \
    acc += (kbase)[(t) * 8 + 3] * p##3; \
    acc += (kbase)[(t) * 8 + 4] * p##4; \
    acc += (kbase)[(t) * 8 + 5] * p##5; \
    acc += (kbase)[(t) * 8 + 6] * p##6; \
    acc += (kbase)[(t) * 8 + 7] * p##7

// ---------------------------------------------------------------------------
// K1 (fused): grid (16, B), block 128 (R3 topology = best measured).
//   role in [0,8):  edge chunk -> em[b,:] += sum_i edge[b,i,:]*ka[b,i]
//   role in [8,16): node chunk -> kf[b,:] += sum_n node[b,n,:]*ka[b,n]
//                                 + out_att chunk (+ out_sp once)
// Inner loops: asm-forced 2x8 float4 double-batch pipeline, 16 loads
// (256B) in flight per thread, counted vmcnt(8) waits (never 0 mid-loop).
// R9 bug fixed: node-role reduction store is guarded (tid>=64 only) --
// the ternary form was a write-write race on red[0..63].
// ---------------------------------------------------------------------------
__global__ __launch_bounds__(128) void k1_fused(
    const float* __restrict__ node, const float* __restrict__ edge,
    const float* __restrict__ att, const float* __restrict__ spi,
    float* __restrict__ out_att, float* __restrict__ out_sp,
    float* __restrict__ kf, float* __restrict__ em) {
    const int b = blockIdx.y;
    const int role = blockIdx.x;
    const int tid = threadIdx.x;
    __shared__ float sps[S];
    __shared__ float kal[64];
    __shared__ f32x4 red[64];
    if (tid < S) sps[tid] = spi[b * S + tid];
    __syncthreads();

    if (role < 8) {
        // ---- edge chunk: 64 rows x 512 cols; each thread all 64 rows of
        //      its float4 column c ----
        const int i0 = role * 64;
        if (tid < 64) {
            const float4* a = reinterpret_cast<const float4*>(att + ((size_t)(b * N + i0 + tid)) * S);
            float4 a0 = a[0], a1 = a[1];
            kal[tid] = a0.x * sps[0] + a0.y * sps[1] + a0.z * sps[2] + a0.w * sps[3]
                     + a1.x * sps[4] + a1.y * sps[5] + a1.z * sps[6] + a1.w * sps[7];
        }
        __syncthreads();                 // drains vmcnt before pipeline starts
        const int c = tid;               // float4 column 0..127
        const float* gb = edge + ((size_t)b * N + i0) * N + (size_t)c * 4;
        f32x4 acc = {0.f, 0.f, 0.f, 0.f};
        f32x4 pa0, pa1, pa2, pa3, pa4, pa5, pa6, pa7;
        f32x4 pb0, pb1, pb2, pb3, pb4, pb5, pb6, pb7;
        LD8(pa, gb, 0, N);
        LD8(pb, gb, 1, N);
        // t=0..7, alternating batches; re-issue 2 ahead
        WAIT8(pa, "8"); CONS8(pa, kal, 0); LD8(pa, gb, 2, N);
        WAIT8(pb, "8"); CONS8(pb, kal, 1); LD8(pb, gb, 3, N);
        WAIT8(pa, "8"); CONS8(pa, kal, 2); LD8(pa, gb, 4, N);
        WAIT8(pb, "8"); CONS8(pb, kal, 3); LD8(pb, gb, 5, N);
        WAIT8(pa, "8"); CONS8(pa, kal, 4); LD8(pa, gb, 6, N);
        WAIT8(pb, "8"); CONS8(pb, kal, 5); LD8(pb, gb, 7, N);
        WAIT8(pa, "8"); CONS8(pa, kal, 6);
        WAIT8(pb, "0"); CONS8(pb, kal, 7);

        float* dst = em + b * N + c * 4;
        unsafeAtomicAdd(dst + 0, acc.x);
        unsafeAtomicAdd(dst + 1, acc.y);
        unsafeAtomicAdd(dst + 2, acc.z);
        unsafeAtomicAdd(dst + 3, acc.w);
    } else {
        // ---- node chunk: 64 rows x 256 cols (+ stack outputs) ----
        const int n0 = (role - 8) * 64;
        if (tid < 64) {
            const float4* a = reinterpret_cast<const float4*>(att + ((size_t)(b * N + n0 + tid)) * S);
            float4 a0 = a[0], a1 = a[1];
            kal[tid] = a0.x * sps[0] + a0.y * sps[1] + a0.z * sps[2] + a0.w * sps[3]
                     + a1.x * sps[4] + a1.y * sps[5] + a1.z * sps[6] + a1.w * sps[7];
            float4 o0 = make_float4(a0.x * (1.f - sps[0]), a0.y * (1.f - sps[1]),
                                    a0.z * (1.f - sps[2]), a0.w * (1.f - sps[3]));
            float4 o1 = make_float4(a1.x * (1.f - sps[4]), a1.y * (1.f - sps[5]),
                                    a1.z * (1.f - sps[6]), a1.w * (1.f - sps[7]));
            float4* oa = reinterpret_cast<float4*>(out_att + ((size_t)(b * N + n0 + tid)) * S);
            oa[0] = o0;
            oa[1] = o1;
        }
        if (role == 8 && tid < S) {
            float v = (tid < S - 1) ? sps[tid + 1] : 0.0f;
            if (tid == 0) v += sps[0];
            out_sp[b * S + tid] = v;
        }
        __syncthreads();                 // drains att loads + out_att stores
        const int c = tid & 63;          // float4 column 0..63
        const int r0 = (tid >> 6) * 32;  // row half: 0 or 32
        const float* gb = node + ((size_t)(b * N + n0 + r0)) * D + (size_t)c * 4;
        const float* kb = kal + r0;
        f32x4 acc = {0.f, 0.f, 0.f, 0.f};
        f32x4 pa0, pa1, pa2, pa3, pa4, pa5, pa6, pa7;
        f32x4 pb0, pb1, pb2, pb3, pb4, pb5, pb6, pb7;
        LD8(pa, gb, 0, D);
        LD8(pb, gb, 1, D);
        WAIT8(pa, "8"); CONS8(pa, kb, 0); LD8(pa, gb, 2, D);
        WAIT8(pb, "8"); CONS8(pb, kb, 1); LD8(pb, gb, 3, D);
        WAIT8(pa, "8"); CONS8(pa, kb, 2);
        WAIT8(pb, "0"); CONS8(pb, kb, 3);

        if (tid >= 64) red[c] = acc;     // upper half publishes
        __syncthreads();
        if (tid < 64) {
            f32x4 s = acc + red[c];
            float* dst = kf + b * D + c * 4;
            unsafeAtomicAdd(dst + 0, s.x);
            unsafeAtomicAdd(dst + 1, s.y);
            unsafeAtomicAdd(dst + 2, s.z);
            unsafeAtomicAdd(dst + 3, s.w);
        }
    }
}

// ---------------------------------------------------------------------------
// K2: q[b,d] = bias[d] + sum_k W[d,k] * kf[b,k]   (grid B, block D)
// ---------------------------------------------------------------------------
__global__ void kC_q(const float* __restrict__ Wm,
                     const float* __restrict__ bias,
                     const float* __restrict__ kf,
                     float* __restrict__ q) {
    const int b = blockIdx.x;
    const int d = threadIdx.x;
    __shared__ float kfl[D];
    kfl[d] = kf[b * D + d];
    __syncthreads();
    float acc = bias[d];
    const float4* wrow = reinterpret_cast<const float4*>(Wm + (size_t)d * D);
    const float4* kf4 = reinterpret_cast<const float4*>(kfl);
    float4 w[8];
    for (int k0 = 0; k0 < D / 4; k0 += 8) {
        #pragma unroll
        for (int u = 0; u < 8; ++u) w[u] = wrow[k0 + u];
        #pragma unroll
        for (int u = 0; u < 8; ++u) {
            float4 f = kf4[k0 + u];
            acc += w[u].x * f.x + w[u].y * f.y + w[u].z * f.z + w[u].w * f.w;
        }
    }
    q[b * D + d] = acc;
}

// ---------------------------------------------------------------------------
// K3: out_vm[b,n] = vm[b,n] + em[b,n] * dot(node[b,n,:], q[b,:])
// one wave per row (64 lanes x float4 = 256 floats); 32 rows per block.
// ---------------------------------------------------------------------------
__global__ void kD_logits(const float* __restrict__ node,
                          const float* __restrict__ em,
                          const float* __restrict__ q,
                          const float* __restrict__ vm,
                          float* __restrict__ out_vm) {
    const int row0 = blockIdx.x * 32;
    const int b = row0 / N;
    const int tid = threadIdx.x;
    const int wave = tid >> 6;
    const int lane = tid & 63;
    __shared__ float ql[D];
    if (tid < D) ql[tid] = q[b * D + tid];
    __syncthreads();
    const float4 q4 = reinterpret_cast<const float4*>(ql)[lane];
    const int wr0 = row0 + wave * 8;
    float emv = 0.f, vmv = 0.f;
    if (lane < 8) {
        emv = em[wr0 + lane];
        vmv = vm[wr0 + lane];
    }
    float4 v[8];
    #pragma unroll
    for (int r = 0; r < 8; ++r)
        v[r] = reinterpret_cast<const float4*>(node + (size_t)(wr0 + r) * D)[lane];
    float myS = 0.f;
    #pragma unroll
    for (int r = 0; r < 8; ++r) {
        float s = v[r].x * q4.x + v[r].y * q4.y + v[r].z * q4.z + v[r].w * q4.w;
        #pragma unroll
        for (int off = 32; off; off >>= 1) s += __shfl_xor(s, off);
        if (lane == r) myS = s;
    }
    if (lane < 8) {
        out_vm[wr0 + lane] = vmv + emv * myS;
    }
}

extern "C" void kernel_launch(void* const* d_in, const int* in_sizes, int n_in,
                              void* d_out, int out_size, void* d_ws, size_t ws_size,
                              hipStream_t stream) {
    const float* node = (const float*)d_in[0];
    // d_in[1] = query : unused by the reference computation
    const float* edge = (const float*)d_in[2];
    const float* att  = (const float*)d_in[3];
    const float* sp   = (const float*)d_in[4];
    const float* vm   = (const float*)d_in[5];
    const float* Wm   = (const float*)d_in[6];
    const float* bias = (const float*)d_in[7];

    float* out_att = (float*)d_out;                    // B*N*S
    float* out_sp  = out_att + (size_t)B * N * S;      // B*S
    float* out_vm  = out_sp + (size_t)B * S;           // B*N

    float* ws = (float*)d_ws;
    float* kf = ws;                          // B*D (atomic-accumulated -> zero)
    float* em = kf + (size_t)B * D;          // B*N (atomic-accumulated -> zero)
    float* q  = em + (size_t)B * N;          // B*D

    (void)hipMemsetAsync(kf, 0, (size_t)(B * D + B * N) * sizeof(float), stream);

    k1_fused<<<dim3(16, B), 128, 0, stream>>>(node, edge, att, sp,
                                              out_att, out_sp, kf, em);
    kC_q<<<B, D, 0, stream>>>(Wm, bias, kf, q);
    kD_logits<<<(B * N) / 32, 256, 0, stream>>>(node, em, q, vm, out_vm);
}